// Round 1
// baseline (202.450 us; speedup 1.0000x reference)
//
#include <hip/hip_runtime.h>
#include <stdint.h>

#define NIMG 32
#define H 1024
#define W 1024
#define BH 73
#define BW 73
#define NCHUNK (NIMG * BH)        // 2336 (one chunk = one (n, by) strip of 73 blocks)
#define TOTAL (NIMG * BH * BW)    // 170528
#define BS 14                     // block stride
#define KW 16                     // pool window

// ---------------------------------------------------------------------------
// Kernel 1: per-(n,by) strip — pooled max over 16x16 windows (stride 14,
// pad 1), flag = max > 0.5, per-chunk active count, prefill output with fill
// triples (32,73,73).
// ---------------------------------------------------------------------------
__global__ __launch_bounds__(256) void pool_kernel(const float* __restrict__ mask,
                                                   uint8_t* __restrict__ flags,
                                                   int* __restrict__ counts,
                                                   int* __restrict__ out_idx) {
    int chunk = blockIdx.x;           // n*73 + by
    int n  = chunk / BH;
    int by = chunk - n * BH;
    const float* img = mask + (size_t)n * (H * W);
    int t = threadIdx.x;              // 0..255

    // --- column max over the 16 window rows; thread t owns cols 4t..4t+3 ---
    int y0 = by * BS - 1;             // first padded-window row in image coords
    int rstart = (y0 < 0) ? -y0 : 0;  // skip the zero-pad row for by==0
    float4 acc = make_float4(-INFINITY, -INFINITY, -INFINITY, -INFINITY);
#pragma unroll
    for (int r = 0; r < KW; ++r) {
        if (r < rstart) continue;     // (y0+15 <= 1022, no upper clamp needed)
        int y = y0 + r;
        float4 v = ((const float4*)(img + (size_t)y * W))[t];
        acc.x = fmaxf(acc.x, v.x);
        acc.y = fmaxf(acc.y, v.y);
        acc.z = fmaxf(acc.z, v.z);
        acc.w = fmaxf(acc.w, v.w);
    }
    __shared__ float colmax[W];
    ((float4*)colmax)[t] = acc;
    __syncthreads();

    // --- 73 window maxes over colmax, flag, prefill ---
    int flag = 0;
    if (t < BW) {
        int x0 = t * BS - 1;
        float m = -INFINITY;
#pragma unroll
        for (int c = 0; c < KW; ++c) {
            int x = x0 + c;
            if (x >= 0) m = fmaxf(m, colmax[x]);   // x <= 1022 always
        }
        flag = (m > 0.5f) ? 1 : 0;
        flags[chunk * BW + t] = (uint8_t)flag;
        // prefill this chunk's output slots with the fill triple (n,bh,bw)
        int s = (chunk * BW + t) * 3;
        out_idx[s]     = NIMG;
        out_idx[s + 1] = BH;
        out_idx[s + 2] = BW;
    }

    // --- per-chunk active count via wave ballots ---
    unsigned long long b = __ballot(flag);
    __shared__ int wsum[4];
    int wave = t >> 6;
    if ((t & 63) == 0) wsum[wave] = __popcll(b);
    __syncthreads();
    if (t == 0) counts[chunk] = wsum[0] + wsum[1] + wsum[2] + wsum[3];
}

// ---------------------------------------------------------------------------
// Kernel 2: exclusive scan of the 2336 chunk counts (single workgroup).
// Thread t owns contiguous items 3t..3t+2; Hillis-Steele over thread sums.
// ---------------------------------------------------------------------------
__global__ __launch_bounds__(1024) void scan_kernel(const int* __restrict__ counts,
                                                    int* __restrict__ offsets,
                                                    int* __restrict__ out_count) {
    __shared__ int lds[1024];
    int t = threadIdx.x;
    int i0 = 3 * t, i1 = i0 + 1, i2 = i0 + 2;
    int a0 = (i0 < NCHUNK) ? counts[i0] : 0;
    int a1 = (i1 < NCHUNK) ? counts[i1] : 0;
    int a2 = (i2 < NCHUNK) ? counts[i2] : 0;
    int s = a0 + a1 + a2;
    lds[t] = s;
    __syncthreads();
    for (int d = 1; d < 1024; d <<= 1) {
        int v = (t >= d) ? lds[t - d] : 0;
        __syncthreads();
        lds[t] += v;
        __syncthreads();
    }
    int ex = lds[t] - s;              // exclusive prefix of this thread's items
    if (i0 < NCHUNK) offsets[i0] = ex;
    if (i1 < NCHUNK) offsets[i1] = ex + a0;
    if (i2 < NCHUNK) offsets[i2] = ex + a0 + a1;
    if (t == 1023) *out_count = lds[1023];   // total active count
}

// ---------------------------------------------------------------------------
// Kernel 3: scatter active triples to their compacted positions.
// ---------------------------------------------------------------------------
__global__ __launch_bounds__(128) void scatter_kernel(const uint8_t* __restrict__ flags,
                                                      const int* __restrict__ offsets,
                                                      int* __restrict__ out_idx) {
    int chunk = blockIdx.x;
    int n  = chunk / BH;
    int by = chunk - n * BH;
    int t = threadIdx.x;              // 0..127, first 73 carry flags
    int flag = (t < BW) ? (int)flags[chunk * BW + t] : 0;
    unsigned long long b = __ballot(flag);
    int lane = t & 63;
    int prefix = __popcll(b & ((1ull << lane) - 1ull));
    __shared__ int w0;
    if (t == 0) w0 = __popcll(b);     // wave 0 total (wave 1 appends after it)
    __syncthreads();
    int pos = prefix + ((t >= 64) ? w0 : 0);
    if (flag) {
        int o = (offsets[chunk] + pos) * 3;
        out_idx[o]     = n;
        out_idx[o + 1] = by;
        out_idx[o + 2] = t;
    }
}

extern "C" void kernel_launch(void* const* d_in, const int* in_sizes, int n_in,
                              void* d_out, int out_size, void* d_ws, size_t ws_size,
                              hipStream_t stream) {
    const float* mask = (const float*)d_in[0];
    int* out = (int*)d_out;

    // workspace layout: flags [0,170528) bytes; counts @170624; offsets after.
    uint8_t* flags = (uint8_t*)d_ws;
    int* counts  = (int*)((char*)d_ws + 170624);
    int* offsets = counts + NCHUNK;

    pool_kernel<<<NCHUNK, 256, 0, stream>>>(mask, flags, counts, out);
    scan_kernel<<<1, 1024, 0, stream>>>(counts, offsets, out + (size_t)TOTAL * 3);
    scatter_kernel<<<NCHUNK, 128, 0, stream>>>(flags, offsets, out);
}